// Round 1
// baseline (811.094 us; speedup 1.0000x reference)
//
#include <hip/hip_runtime.h>
#include <cstdint>

typedef unsigned int u32;
typedef unsigned short u16;
typedef float fx4 __attribute__((ext_vector_type(4)));
typedef __bf16 bfx8 __attribute__((ext_vector_type(8)));

// ---------- helpers ----------
__device__ __forceinline__ u16 f2bf(float f) {
  u32 u = __builtin_bit_cast(u32, f);
  u32 r = (u + 0x7fffu + ((u >> 16) & 1u)) >> 16;  // RNE
  return (u16)r;
}
__device__ __forceinline__ float bf2f(u16 v) {
  return __builtin_bit_cast(float, (u32)v << 16);
}
// async global->LDS, 16B per lane (gfx950). LDS dest = wave-uniform base + lane*16.
__device__ __forceinline__ void async_copy16(const void* g, void* l) {
  auto gp = reinterpret_cast<__attribute__((address_space(1))) void*>((uintptr_t)g);
  auto lp = reinterpret_cast<__attribute__((address_space(3))) void*>((uintptr_t)l);
  __builtin_amdgcn_global_load_lds(gp, lp, 16, 0, 0);
}

// ---------- fp32 -> bf16 conversion of x, c, 8 weights ----------
__global__ __launch_bounds__(256) void cvt_all(
    const float* __restrict__ x, const float* __restrict__ c,
    const float* __restrict__ w0, const float* __restrict__ w1,
    const float* __restrict__ w2, const float* __restrict__ w3,
    const float* __restrict__ w4, const float* __restrict__ w5,
    const float* __restrict__ w6, const float* __restrict__ w7,
    u16* __restrict__ xb, u16* __restrict__ cb, u16* __restrict__ wb) {
  const int i = blockIdx.x * 256 + threadIdx.x;  // float4 index
  const float* src;
  u16* dst;
  size_t off;
  if (i < 4194304) {            // x: 16777216 floats
    src = x; dst = xb; off = (size_t)i;
  } else if (i < 4456448) {     // c: 1048576 floats
    src = c; dst = cb; off = (size_t)(i - 4194304);
  } else {                      // 8 weights, 1048576 floats each
    const int r = i - 4456448;
    const int wsel = r >> 18;
    off = (size_t)(r & 262143);
    switch (wsel) {
      case 0: src = w0; break; case 1: src = w1; break;
      case 2: src = w2; break; case 3: src = w3; break;
      case 4: src = w4; break; case 5: src = w5; break;
      case 6: src = w6; break; default: src = w7; break;
    }
    dst = wb + (size_t)wsel * 1048576;
  }
  const fx4 v = *(const fx4*)(src + off * 4);
  uint2 o;
  o.x = (u32)f2bf(v[0]) | ((u32)f2bf(v[1]) << 16);
  o.y = (u32)f2bf(v[2]) | ((u32)f2bf(v[3]) << 16);
  *(uint2*)(dst + off * 4) = o;
}

// ---------- NT GEMM: C[M,Nc] (fp32) = A[M,K] (bf16) * Bw[Nc,K]^T (bf16) ----------
// 128x128 block tile, 4 waves in 2x2, each wave 64x64 via 4x4 mfma_f32_16x16x32_bf16.
__global__ __launch_bounds__(256) void gemm_nt(
    const u16* __restrict__ A, const u16* __restrict__ Bw, float* __restrict__ C,
    int M, int Nc, int K) {
  __shared__ __align__(16) u16 As[128 * 64];
  __shared__ __align__(16) u16 Bs[128 * 64];
  const int t = threadIdx.x;
  const int w = t >> 6;
  const int lane = t & 63;
  const int lr = lane & 15;
  const int quad = lane >> 4;
  const int m0 = (w & 1) * 64;
  const int n0 = (w >> 1) * 64;
  const long rowBase = (long)blockIdx.y * 128;
  const long colBase = (long)blockIdx.x * 128;

  fx4 acc[4][4] = {};
  const int f0 = t * 8;

  for (int k0 = 0; k0 < K; k0 += 64) {
#pragma unroll
    for (int r = 0; r < 4; ++r) {
      const int f = f0 + r * 2048;        // flat bf16 index in 128x64 tile
      const int row = f >> 6;
      const int col = f & 63;
      async_copy16(A + (rowBase + row) * K + (k0 + col), &As[f]);
      async_copy16(Bw + (colBase + row) * K + (k0 + col), &Bs[f]);
    }
    __syncthreads();  // compiler drains vmcnt before s_barrier
#pragma unroll
    for (int ks = 0; ks < 2; ++ks) {
      bfx8 af[4], bfr[4];
#pragma unroll
      for (int i = 0; i < 4; ++i)
        af[i] = *(const bfx8*)&As[(m0 + i * 16 + lr) * 64 + ks * 32 + quad * 8];
#pragma unroll
      for (int i = 0; i < 4; ++i)
        bfr[i] = *(const bfx8*)&Bs[(n0 + i * 16 + lr) * 64 + ks * 32 + quad * 8];
#pragma unroll
      for (int mi = 0; mi < 4; ++mi)
#pragma unroll
        for (int ni = 0; ni < 4; ++ni)
          acc[mi][ni] =
              __builtin_amdgcn_mfma_f32_16x16x32_bf16(af[mi], bfr[ni], acc[mi][ni], 0, 0, 0);
    }
    __syncthreads();
  }
  // C/D layout: col = lane&15, row = quad*4 + reg  (m89/m91 verified)
#pragma unroll
  for (int mi = 0; mi < 4; ++mi)
#pragma unroll
    for (int ni = 0; ni < 4; ++ni) {
      const long col = colBase + n0 + ni * 16 + lr;
#pragma unroll
      for (int r = 0; r < 4; ++r) {
        const long row = rowBase + m0 + mi * 16 + quad * 4 + r;
        C[row * Nc + col] = acc[mi][ni][r];
      }
    }
}

// ---------- l2 norm per 64-element head segment: fp32 -> bf16 ----------
__global__ __launch_bounds__(256) void norm_segs(const float* __restrict__ P,
                                                 u16* __restrict__ O) {
  const int seg = blockIdx.x * 4 + (threadIdx.x >> 6);
  const int lane = threadIdx.x & 63;
  const float v = P[(size_t)seg * 64 + lane];
  float s = v * v;
#pragma unroll
  for (int off = 32; off; off >>= 1) s += __shfl_xor(s, off, 64);
  const float n = fmaxf(sqrtf(s), 1e-12f);
  O[(size_t)seg * 64 + lane] = f2bf(v / n);
}

// ---------- v scaling: v * 4352^(-sigmoid(nc[h])) : fp32 -> bf16 ----------
__global__ __launch_bounds__(256) void vscale(const float* __restrict__ P,
                                              const float* __restrict__ nc,
                                              u16* __restrict__ O) {
  const size_t i = (size_t)blockIdx.x * 256 + threadIdx.x;
  const int h = (int)((i >> 6) & 15);
  // scale = exp(-ln(4352) * sigmoid(nc[h])),  ln(4352) = 8.3783908
  const float s = expf(-8.3783908f / (1.f + expf(-nc[h])));
  O[i] = f2bf(P[i] * s);
}

// ---------- kv partials: kv[bh][d][e] += sum_n K[n,d]*V[n,e] over 256-row split ----------
__global__ __launch_bounds__(256) void kv_partial(
    const u16* __restrict__ Kx, const u16* __restrict__ Vx,
    const u16* __restrict__ Kc, const u16* __restrict__ Vc,
    float* __restrict__ part) {
  const int split = blockIdx.x;  // 0..15: x rows, 16: c rows
  const int bh = blockIdx.y;
  const int b = bh >> 4, h = bh & 15;
  const u16* Kp;
  const u16* Vp;
  size_t rowBase;
  if (split < 16) { Kp = Kx; Vp = Vx; rowBase = (size_t)b * 4096 + (size_t)split * 256; }
  else           { Kp = Kc; Vp = Vc; rowBase = (size_t)b * 256; }

  __shared__ __align__(16) float Ks[64 * 64];
  __shared__ __align__(16) float Vs[64 * 64];
  const int t = threadIdx.x;
  const int db = (t >> 4) * 4;
  const int eb = (t & 15) * 4;
  float acc[4][4] = {};

  for (int ch = 0; ch < 4; ++ch) {
#pragma unroll
    for (int j = 0; j < 2; ++j) {
      const int u = t + 256 * j;  // 0..511 : (row, group-of-8)
      const int row = u >> 3, grp = u & 7;
      const size_t goff = (rowBase + ch * 64 + row) * 1024 + h * 64 + grp * 8;
      const uint4 kq = *(const uint4*)(Kp + goff);
      const uint4 vq = *(const uint4*)(Vp + goff);
      float* kd = &Ks[row * 64 + grp * 8];
      float* vd = &Vs[row * 64 + grp * 8];
      kd[0] = bf2f((u16)(kq.x & 0xffff)); kd[1] = bf2f((u16)(kq.x >> 16));
      kd[2] = bf2f((u16)(kq.y & 0xffff)); kd[3] = bf2f((u16)(kq.y >> 16));
      kd[4] = bf2f((u16)(kq.z & 0xffff)); kd[5] = bf2f((u16)(kq.z >> 16));
      kd[6] = bf2f((u16)(kq.w & 0xffff)); kd[7] = bf2f((u16)(kq.w >> 16));
      vd[0] = bf2f((u16)(vq.x & 0xffff)); vd[1] = bf2f((u16)(vq.x >> 16));
      vd[2] = bf2f((u16)(vq.y & 0xffff)); vd[3] = bf2f((u16)(vq.y >> 16));
      vd[4] = bf2f((u16)(vq.z & 0xffff)); vd[5] = bf2f((u16)(vq.z >> 16));
      vd[6] = bf2f((u16)(vq.w & 0xffff)); vd[7] = bf2f((u16)(vq.w >> 16));
    }
    __syncthreads();
#pragma unroll 4
    for (int n = 0; n < 64; ++n) {
      const fx4 kd = *(const fx4*)&Ks[n * 64 + db];
      const fx4 ve = *(const fx4*)&Vs[n * 64 + eb];
#pragma unroll
      for (int i = 0; i < 4; ++i)
#pragma unroll
        for (int j = 0; j < 4; ++j)
          acc[i][j] += kd[i] * ve[j];
    }
    __syncthreads();
  }
  float* pp = part + ((size_t)bh * 17 + split) * 4096;
#pragma unroll
  for (int i = 0; i < 4; ++i)
#pragma unroll
    for (int j = 0; j < 4; ++j)
      pp[(db + i) * 64 + (eb + j)] = acc[i][j];
}

__global__ __launch_bounds__(256) void kv_reduce(const float* __restrict__ part,
                                                 float* __restrict__ kv) {
  const int i = blockIdx.x * 256 + threadIdx.x;  // 64*4096
  const int bh = i >> 12;
  const int de = i & 4095;
  float s = 0.f;
#pragma unroll
  for (int sp = 0; sp < 17; ++sp) s += part[((size_t)bh * 17 + sp) * 4096 + de];
  kv[i] = s;
}

// ---------- attn = q @ kv, per (b,h); one wave per sequence row ----------
__global__ __launch_bounds__(256) void attn_apply(
    const u16* __restrict__ Q, const float* __restrict__ kv, u16* __restrict__ Aout,
    int seqPerBatch) {
  const int bh = blockIdx.y;
  const int b = bh >> 4, h = bh & 15;
  __shared__ __align__(16) float kvT[64][68];  // [e][d], +4 pad
  const int t = threadIdx.x;
#pragma unroll
  for (int j = 0; j < 4; ++j) {
    const int idx = (t + 256 * j) * 4;
    const fx4 v = *(const fx4*)&kv[(size_t)bh * 4096 + idx];
    const int d = idx >> 6;
    const int e0 = idx & 63;
    kvT[e0 + 0][d] = v[0];
    kvT[e0 + 1][d] = v[1];
    kvT[e0 + 2][d] = v[2];
    kvT[e0 + 3][d] = v[3];
  }
  __syncthreads();
  const int w = t >> 6;
  const int lane = t & 63;
  for (int it = 0; it < 8; ++it) {
    const int row = blockIdx.x * 32 + it * 4 + w;
    const size_t base = ((size_t)b * seqPerBatch + row) * 1024 + (size_t)h * 64;
    const float qv = bf2f(Q[base + lane]);
    float acc = 0.f;
#pragma unroll
    for (int d4 = 0; d4 < 16; ++d4) {
      const fx4 kvv = *(const fx4*)&kvT[lane][d4 * 4];
      acc += __shfl(qv, d4 * 4 + 0, 64) * kvv[0];
      acc += __shfl(qv, d4 * 4 + 1, 64) * kvv[1];
      acc += __shfl(qv, d4 * 4 + 2, 64) * kvv[2];
      acc += __shfl(qv, d4 * 4 + 3, 64) * kvv[3];
    }
    Aout[base + lane] = f2bf(acc);
  }
}

// ---------- launch ----------
extern "C" void kernel_launch(void* const* d_in, const int* in_sizes, int n_in,
                              void* d_out, int out_size, void* d_ws, size_t ws_size,
                              hipStream_t stream) {
  (void)in_sizes; (void)n_in; (void)out_size; (void)ws_size;
  const float* x = (const float*)d_in[0];
  const float* c = (const float*)d_in[1];
  const float* nc = (const float*)d_in[10];
  float* out = (float*)d_out;
  char* ws = (char*)d_ws;

  // workspace layout (bytes). total = 230,686,720
  u16* Xb = (u16*)(ws + 0);                       // 33,554,432
  u16* Cb = (u16*)(ws + 33554432);                //  2,097,152
  u16* Wb = (u16*)(ws + 35651584);                // 16,777,216 (8 weights bf16)
  float* P = (float*)(ws + 52428800);             // 67,108,864 fp32 proj scratch (x)
  // aliases inside P region, used only after projections complete:
  u16* Ax = (u16*)(ws + 52428800);                // 33,554,432
  u16* Ac = (u16*)(ws + 52428800 + 33554432);     //  2,097,152
  float* part = (float*)(ws + 52428800 + 35651584);  // 17,825,792
  float* kvb = (float*)(ws + 52428800 + 53477376);   //  1,048,576
  float* Pc = (float*)(ws + 119537664);           //  4,194,304 fp32 proj scratch (c)
  u16* Qx = (u16*)(ws + 123731968);
  u16* Kx = (u16*)(ws + 157286400);
  u16* Vx = (u16*)(ws + 190840832);
  u16* Qc = (u16*)(ws + 224395264);
  u16* Kc = (u16*)(ws + 226492416);
  u16* Vc = (u16*)(ws + 228589568);

  cvt_all<<<25600, 256, 0, stream>>>(
      x, c, (const float*)d_in[2], (const float*)d_in[3], (const float*)d_in[4],
      (const float*)d_in[5], (const float*)d_in[6], (const float*)d_in[7],
      (const float*)d_in[8], (const float*)d_in[9], Xb, Cb, Wb);

  // x-stream projections (M=16384)
  gemm_nt<<<dim3(8, 128), 256, 0, stream>>>(Xb, Wb + 0 * 1048576, P, 16384, 1024, 1024);
  norm_segs<<<65536, 256, 0, stream>>>(P, Qx);
  gemm_nt<<<dim3(8, 128), 256, 0, stream>>>(Xb, Wb + 1 * 1048576, P, 16384, 1024, 1024);
  norm_segs<<<65536, 256, 0, stream>>>(P, Kx);
  gemm_nt<<<dim3(8, 128), 256, 0, stream>>>(Xb, Wb + 2 * 1048576, P, 16384, 1024, 1024);
  vscale<<<65536, 256, 0, stream>>>(P, nc, Vx);
  // c-stream projections (M=1024)
  gemm_nt<<<dim3(8, 8), 256, 0, stream>>>(Cb, Wb + 3 * 1048576, Pc, 1024, 1024, 1024);
  norm_segs<<<4096, 256, 0, stream>>>(Pc, Qc);
  gemm_nt<<<dim3(8, 8), 256, 0, stream>>>(Cb, Wb + 4 * 1048576, Pc, 1024, 1024, 1024);
  norm_segs<<<4096, 256, 0, stream>>>(Pc, Kc);
  gemm_nt<<<dim3(8, 8), 256, 0, stream>>>(Cb, Wb + 5 * 1048576, Pc, 1024, 1024, 1024);
  vscale<<<4096, 256, 0, stream>>>(Pc, nc, Vc);
  // kv = k^T v over concatenated sequence (16 x-splits + 1 c-split), then reduce
  kv_partial<<<dim3(17, 64), 256, 0, stream>>>(Kx, Vx, Kc, Vc, part);
  kv_reduce<<<1024, 256, 0, stream>>>(part, kvb);
  // attn = q @ kv
  attn_apply<<<dim3(128, 64), 256, 0, stream>>>(Qx, kvb, Ax, 4096);
  attn_apply<<<dim3(8, 64), 256, 0, stream>>>(Qc, kvb, Ac, 256);
  // output projections straight into d_out (fp32)
  gemm_nt<<<dim3(8, 128), 256, 0, stream>>>(Ax, Wb + 6 * 1048576, out, 16384, 1024, 1024);
  gemm_nt<<<dim3(8, 8), 256, 0, stream>>>(Ac, Wb + 7 * 1048576, out + 16777216, 1024, 1024, 1024);
}

// Round 2
// 541.778 us; speedup vs baseline: 1.4971x; 1.4971x over previous
//
#include <hip/hip_runtime.h>
#include <cstdint>

typedef unsigned int u32;
typedef unsigned short u16;
typedef float fx4 __attribute__((ext_vector_type(4)));
typedef __bf16 bfx8 __attribute__((ext_vector_type(8)));

// ---------- helpers ----------
__device__ __forceinline__ u16 f2bf(float f) {
  u32 u = __builtin_bit_cast(u32, f);
  u32 r = (u + 0x7fffu + ((u >> 16) & 1u)) >> 16;  // RNE
  return (u16)r;
}
__device__ __forceinline__ float bf2f(u16 v) {
  return __builtin_bit_cast(float, (u32)v << 16);
}
// async global->LDS, 16B per lane (gfx950). LDS dest = wave-uniform base + lane*16.
__device__ __forceinline__ void async_copy16(const void* g, void* l) {
  auto gp = reinterpret_cast<__attribute__((address_space(1))) void*>((uintptr_t)g);
  auto lp = reinterpret_cast<__attribute__((address_space(3))) void*>((uintptr_t)l);
  __builtin_amdgcn_global_load_lds(gp, lp, 16, 0, 0);
}

// ---------- fp32 -> bf16 conversion of x, c, 8 weights ----------
__global__ __launch_bounds__(256) void cvt_all(
    const float* __restrict__ x, const float* __restrict__ c,
    const float* __restrict__ w0, const float* __restrict__ w1,
    const float* __restrict__ w2, const float* __restrict__ w3,
    const float* __restrict__ w4, const float* __restrict__ w5,
    const float* __restrict__ w6, const float* __restrict__ w7,
    u16* __restrict__ xb, u16* __restrict__ cb, u16* __restrict__ wb) {
  const int i = blockIdx.x * 256 + threadIdx.x;  // float4 index
  const float* src;
  u16* dst;
  size_t off;
  if (i < 4194304) {            // x: 16777216 floats
    src = x; dst = xb; off = (size_t)i;
  } else if (i < 4456448) {     // c: 1048576 floats
    src = c; dst = cb; off = (size_t)(i - 4194304);
  } else {                      // 8 weights, 1048576 floats each
    const int r = i - 4456448;
    const int wsel = r >> 18;
    off = (size_t)(r & 262143);
    switch (wsel) {
      case 0: src = w0; break; case 1: src = w1; break;
      case 2: src = w2; break; case 3: src = w3; break;
      case 4: src = w4; break; case 5: src = w5; break;
      case 6: src = w6; break; default: src = w7; break;
    }
    dst = wb + (size_t)wsel * 1048576;
  }
  const fx4 v = *(const fx4*)(src + off * 4);
  uint2 o;
  o.x = (u32)f2bf(v[0]) | ((u32)f2bf(v[1]) << 16);
  o.y = (u32)f2bf(v[2]) | ((u32)f2bf(v[3]) << 16);
  *(uint2*)(dst + off * 4) = o;
}

// ---------- NT GEMM: C[M,Nc] = A[M,K] (bf16) * Bw[Nc,K]^T (bf16) ----------
// 128x128 block tile, 4 waves in 2x2, each wave 64x64 via 4x4 mfma_f32_16x16x32_bf16.
// MODE 0: C fp32 (batched via blockIdx.z strides)
// MODE 1: per-row l2norm over the wave's 64-col head segment, C bf16
// MODE 2: per-head v-scale  v * 4352^(-sigmoid(nc[h])), C bf16
template <int MODE>
__global__ __launch_bounds__(256) void gemm_nt(
    const u16* __restrict__ A, const u16* __restrict__ Bw, void* __restrict__ Cv,
    int M, int Nc, int K, long sA, long sB, long sC, const float* __restrict__ nc) {
  __shared__ __align__(16) u16 As[128 * 64];
  __shared__ __align__(16) u16 Bs[128 * 64];
  A += (long)blockIdx.z * sA;
  Bw += (long)blockIdx.z * sB;
  const int t = threadIdx.x;
  const int w = t >> 6;
  const int lane = t & 63;
  const int lr = lane & 15;
  const int quad = lane >> 4;
  const int m0 = (w & 1) * 64;
  const int n0 = (w >> 1) * 64;
  const long rowBase = (long)blockIdx.y * 128;
  const long colBase = (long)blockIdx.x * 128;

  fx4 acc[4][4] = {};
  const int f0 = t * 8;

  for (int k0 = 0; k0 < K; k0 += 64) {
#pragma unroll
    for (int r = 0; r < 4; ++r) {
      const int f = f0 + r * 2048;        // flat bf16 index in 128x64 tile
      const int row = f >> 6;
      const int col = f & 63;
      async_copy16(A + (rowBase + row) * K + (k0 + col), &As[f]);
      async_copy16(Bw + (colBase + row) * K + (k0 + col), &Bs[f]);
    }
    __syncthreads();
#pragma unroll
    for (int ks = 0; ks < 2; ++ks) {
      bfx8 af[4], bfr[4];
#pragma unroll
      for (int i = 0; i < 4; ++i)
        af[i] = *(const bfx8*)&As[(m0 + i * 16 + lr) * 64 + ks * 32 + quad * 8];
#pragma unroll
      for (int i = 0; i < 4; ++i)
        bfr[i] = *(const bfx8*)&Bs[(n0 + i * 16 + lr) * 64 + ks * 32 + quad * 8];
#pragma unroll
      for (int mi = 0; mi < 4; ++mi)
#pragma unroll
        for (int ni = 0; ni < 4; ++ni)
          acc[mi][ni] =
              __builtin_amdgcn_mfma_f32_16x16x32_bf16(af[mi], bfr[ni], acc[mi][ni], 0, 0, 0);
    }
    __syncthreads();
  }
  // C/D layout: col = lane&15, row = quad*4 + reg
  if (MODE == 0) {
    float* C = (float*)Cv + (long)blockIdx.z * sC;
#pragma unroll
    for (int mi = 0; mi < 4; ++mi)
#pragma unroll
      for (int ni = 0; ni < 4; ++ni) {
        const long col = colBase + n0 + ni * 16 + lr;
#pragma unroll
        for (int r = 0; r < 4; ++r) {
          const long row = rowBase + m0 + mi * 16 + quad * 4 + r;
          C[row * Nc + col] = acc[mi][ni][r];
        }
      }
  } else if (MODE == 1) {
    u16* C = (u16*)Cv;
#pragma unroll
    for (int mi = 0; mi < 4; ++mi) {
      float ss[4] = {0.f, 0.f, 0.f, 0.f};
#pragma unroll
      for (int ni = 0; ni < 4; ++ni)
#pragma unroll
        for (int r = 0; r < 4; ++r) ss[r] += acc[mi][ni][r] * acc[mi][ni][r];
      // reduce across the 16 lanes (lr) sharing this quad's rows
#pragma unroll
      for (int off = 1; off < 16; off <<= 1)
#pragma unroll
        for (int r = 0; r < 4; ++r) ss[r] += __shfl_xor(ss[r], off, 64);
      float sc[4];
#pragma unroll
      for (int r = 0; r < 4; ++r) sc[r] = 1.f / fmaxf(sqrtf(ss[r]), 1e-12f);
#pragma unroll
      for (int ni = 0; ni < 4; ++ni) {
        const long col = colBase + n0 + ni * 16 + lr;
#pragma unroll
        for (int r = 0; r < 4; ++r) {
          const long row = rowBase + m0 + mi * 16 + quad * 4 + r;
          C[row * Nc + col] = f2bf(acc[mi][ni][r] * sc[r]);
        }
      }
    }
  } else {  // MODE == 2
    u16* C = (u16*)Cv;
    const int h = (int)(((colBase + n0) >> 6) & 15);
    // scale = 4352^(-sigmoid(nc[h])),  ln(4352) = 8.3783908
    const float s = __expf(-8.3783908f / (1.f + __expf(-nc[h])));
#pragma unroll
    for (int mi = 0; mi < 4; ++mi)
#pragma unroll
      for (int ni = 0; ni < 4; ++ni) {
        const long col = colBase + n0 + ni * 16 + lr;
#pragma unroll
        for (int r = 0; r < 4; ++r) {
          const long row = rowBase + m0 + mi * 16 + quad * 4 + r;
          C[row * Nc + col] = f2bf(acc[mi][ni][r] * s);
        }
      }
  }
}

// ---------- kv partials: kv[bh][d][e] += sum_n K[n,d]*V[n,e] over 256-row split ----------
__global__ __launch_bounds__(256) void kv_partial(
    const u16* __restrict__ Kx, const u16* __restrict__ Vx,
    const u16* __restrict__ Kc, const u16* __restrict__ Vc,
    float* __restrict__ part) {
  const int split = blockIdx.x;  // 0..15: x rows, 16: c rows
  const int bh = blockIdx.y;
  const int b = bh >> 4, h = bh & 15;
  const u16* Kp;
  const u16* Vp;
  size_t rowBase;
  if (split < 16) { Kp = Kx; Vp = Vx; rowBase = (size_t)b * 4096 + (size_t)split * 256; }
  else           { Kp = Kc; Vp = Vc; rowBase = (size_t)b * 256; }

  __shared__ __align__(16) float Ks[64 * 64];
  __shared__ __align__(16) float Vs[64 * 64];
  const int t = threadIdx.x;
  const int db = (t >> 4) * 4;
  const int eb = (t & 15) * 4;
  float acc[4][4] = {};

  for (int ch = 0; ch < 4; ++ch) {
#pragma unroll
    for (int j = 0; j < 2; ++j) {
      const int u = t + 256 * j;  // 0..511 : (row, group-of-8)
      const int row = u >> 3, grp = u & 7;
      const size_t goff = (rowBase + ch * 64 + row) * 1024 + h * 64 + grp * 8;
      const uint4 kq = *(const uint4*)(Kp + goff);
      const uint4 vq = *(const uint4*)(Vp + goff);
      float* kd = &Ks[row * 64 + grp * 8];
      float* vd = &Vs[row * 64 + grp * 8];
      kd[0] = bf2f((u16)(kq.x & 0xffff)); kd[1] = bf2f((u16)(kq.x >> 16));
      kd[2] = bf2f((u16)(kq.y & 0xffff)); kd[3] = bf2f((u16)(kq.y >> 16));
      kd[4] = bf2f((u16)(kq.z & 0xffff)); kd[5] = bf2f((u16)(kq.z >> 16));
      kd[6] = bf2f((u16)(kq.w & 0xffff)); kd[7] = bf2f((u16)(kq.w >> 16));
      vd[0] = bf2f((u16)(vq.x & 0xffff)); vd[1] = bf2f((u16)(vq.x >> 16));
      vd[2] = bf2f((u16)(vq.y & 0xffff)); vd[3] = bf2f((u16)(vq.y >> 16));
      vd[4] = bf2f((u16)(vq.z & 0xffff)); vd[5] = bf2f((u16)(vq.z >> 16));
      vd[6] = bf2f((u16)(vq.w & 0xffff)); vd[7] = bf2f((u16)(vq.w >> 16));
    }
    __syncthreads();
#pragma unroll 4
    for (int n = 0; n < 64; ++n) {
      const fx4 kd = *(const fx4*)&Ks[n * 64 + db];
      const fx4 ve = *(const fx4*)&Vs[n * 64 + eb];
#pragma unroll
      for (int i = 0; i < 4; ++i)
#pragma unroll
        for (int j = 0; j < 4; ++j)
          acc[i][j] += kd[i] * ve[j];
    }
    __syncthreads();
  }
  float* pp = part + ((size_t)bh * 17 + split) * 4096;
#pragma unroll
  for (int i = 0; i < 4; ++i)
#pragma unroll
    for (int j = 0; j < 4; ++j)
      pp[(db + i) * 64 + (eb + j)] = acc[i][j];
}

__global__ __launch_bounds__(256) void kv_reduce(const float* __restrict__ part,
                                                 float* __restrict__ kv) {
  const int i = blockIdx.x * 256 + threadIdx.x;  // 64*4096
  const int bh = i >> 12;
  const int de = i & 4095;
  float s = 0.f;
#pragma unroll
  for (int sp = 0; sp < 17; ++sp) s += part[((size_t)bh * 17 + sp) * 4096 + de];
  kv[i] = s;
}

// ---------- Weff[b][o, h*64+d] = sum_e Wo[o, h*64+e] * kv[b,h][d,e]  (bf16 out) ----------
// grid: (o-tile 0..15, bh 0..63, stream 0..1), block 256
__global__ __launch_bounds__(256) void weff_build(
    const u16* __restrict__ WoX, const u16* __restrict__ WoC,
    const float* __restrict__ kvb, u16* __restrict__ WeffX, u16* __restrict__ WeffC) {
  const int ot = blockIdx.x;
  const int bh = blockIdx.y;
  const int b = bh >> 4, h = bh & 15;
  const u16* Wo = blockIdx.z ? WoC : WoX;
  u16* outp = (blockIdx.z ? WeffC : WeffX) + (size_t)b * 1048576;

  __shared__ __align__(16) float kvT[64 * 64];  // [e][d]
  __shared__ __align__(16) float WoT[64 * 64];  // [e][o_local]
  const int t = threadIdx.x;
  // load kv (fp32 [d][e]) transposed
#pragma unroll
  for (int j = 0; j < 4; ++j) {
    const int idx = (t + 256 * j) * 4;  // flat = d*64+e
    const fx4 v = *(const fx4*)&kvb[(size_t)bh * 4096 + idx];
    const int d = idx >> 6;
    const int e0 = idx & 63;
#pragma unroll
    for (int k = 0; k < 4; ++k) kvT[(e0 + k) * 64 + d] = v[k];
  }
  // load Wo tile (bf16, rows ot*64.., cols h*64..) transposed
#pragma unroll
  for (int j = 0; j < 2; ++j) {
    const int u = t + 256 * j;  // 512 groups of 8 bf16
    const int row = u >> 3;     // o_local
    const int e0 = (u & 7) * 8;
    const uint4 q = *(const uint4*)&Wo[(size_t)(ot * 64 + row) * 1024 + h * 64 + e0];
    WoT[(e0 + 0) * 64 + row] = bf2f((u16)(q.x & 0xffff));
    WoT[(e0 + 1) * 64 + row] = bf2f((u16)(q.x >> 16));
    WoT[(e0 + 2) * 64 + row] = bf2f((u16)(q.y & 0xffff));
    WoT[(e0 + 3) * 64 + row] = bf2f((u16)(q.y >> 16));
    WoT[(e0 + 4) * 64 + row] = bf2f((u16)(q.z & 0xffff));
    WoT[(e0 + 5) * 64 + row] = bf2f((u16)(q.z >> 16));
    WoT[(e0 + 6) * 64 + row] = bf2f((u16)(q.w & 0xffff));
    WoT[(e0 + 7) * 64 + row] = bf2f((u16)(q.w >> 16));
  }
  __syncthreads();
  const int ob = (t >> 4) * 4;  // o_local base
  const int db = (t & 15) * 4;  // d base
  float acc[4][4] = {};
#pragma unroll 4
  for (int e = 0; e < 64; ++e) {
    const fx4 wv = *(const fx4*)&WoT[e * 64 + ob];
    const fx4 kvv = *(const fx4*)&kvT[e * 64 + db];
#pragma unroll
    for (int i = 0; i < 4; ++i)
#pragma unroll
      for (int j = 0; j < 4; ++j)
        acc[i][j] += wv[i] * kvv[j];
  }
#pragma unroll
  for (int i = 0; i < 4; ++i)
#pragma unroll
    for (int j = 0; j < 4; ++j)
      outp[(size_t)(ot * 64 + ob + i) * 1024 + h * 64 + db + j] = f2bf(acc[i][j]);
}

// ---------- launch ----------
extern "C" void kernel_launch(void* const* d_in, const int* in_sizes, int n_in,
                              void* d_out, int out_size, void* d_ws, size_t ws_size,
                              hipStream_t stream) {
  (void)in_sizes; (void)n_in; (void)out_size; (void)ws_size;
  const float* x = (const float*)d_in[0];
  const float* c = (const float*)d_in[1];
  const float* nc = (const float*)d_in[10];
  float* out = (float*)d_out;
  char* ws = (char*)d_ws;

  // workspace layout (bytes). total = 195,035,136
  u16* Xb = (u16*)(ws + 0);                 // 33,554,432
  u16* Cb = (u16*)(ws + 33554432);          //  2,097,152
  u16* Wb = (u16*)(ws + 35651584);          // 16,777,216 (8 weights bf16)
  u16* Qx = (u16*)(ws + 52428800);          // 33,554,432
  u16* Kx = (u16*)(ws + 85983232);          // 33,554,432
  u16* Vx = (u16*)(ws + 119537664);         // 33,554,432
  u16* Qc = (u16*)(ws + 153092096);         //  2,097,152
  u16* Kc = (u16*)(ws + 155189248);         //  2,097,152
  u16* Vc = (u16*)(ws + 157286400);         //  2,097,152
  float* part = (float*)(ws + 159383552);   // 17,825,792
  float* kvb = (float*)(ws + 177209344);    //  1,048,576
  u16* Weffx = (u16*)(ws + 178257920);      //  8,388,608
  u16* Weffc = (u16*)(ws + 186646528);      //  8,388,608

  cvt_all<<<25600, 256, 0, stream>>>(
      x, c, (const float*)d_in[2], (const float*)d_in[3], (const float*)d_in[4],
      (const float*)d_in[5], (const float*)d_in[6], (const float*)d_in[7],
      (const float*)d_in[8], (const float*)d_in[9], Xb, Cb, Wb);

  // x-stream projections, fused epilogues (M=16384)
  gemm_nt<1><<<dim3(8, 128), 256, 0, stream>>>(Xb, Wb + 0 * 1048576, Qx, 16384, 1024, 1024, 0, 0, 0, nullptr);
  gemm_nt<1><<<dim3(8, 128), 256, 0, stream>>>(Xb, Wb + 1 * 1048576, Kx, 16384, 1024, 1024, 0, 0, 0, nullptr);
  gemm_nt<2><<<dim3(8, 128), 256, 0, stream>>>(Xb, Wb + 2 * 1048576, Vx, 16384, 1024, 1024, 0, 0, 0, nc);
  // c-stream projections (M=1024)
  gemm_nt<1><<<dim3(8, 8), 256, 0, stream>>>(Cb, Wb + 3 * 1048576, Qc, 1024, 1024, 1024, 0, 0, 0, nullptr);
  gemm_nt<1><<<dim3(8, 8), 256, 0, stream>>>(Cb, Wb + 4 * 1048576, Kc, 1024, 1024, 1024, 0, 0, 0, nullptr);
  gemm_nt<2><<<dim3(8, 8), 256, 0, stream>>>(Cb, Wb + 5 * 1048576, Vc, 1024, 1024, 1024, 0, 0, 0, nc);
  // kv = k^T v over concatenated sequence (16 x-splits + 1 c-split), then reduce
  kv_partial<<<dim3(17, 64), 256, 0, stream>>>(Kx, Vx, Kc, Vc, part);
  kv_reduce<<<1024, 256, 0, stream>>>(part, kvb);
  // fold kv into output projections: Weff[b] = blockdiag(kv) applied to Wo
  weff_build<<<dim3(16, 64, 2), 256, 0, stream>>>(Wb + 6 * 1048576, Wb + 7 * 1048576,
                                                  kvb, Weffx, Weffc);
  // out = q @ Weff[b]^T, batched over b, straight into d_out (fp32)
  gemm_nt<0><<<dim3(8, 32, 4), 256, 0, stream>>>(Qx, Weffx, out, 4096, 1024, 1024,
                                                 4194304, 1048576, 4194304, nullptr);
  gemm_nt<0><<<dim3(8, 2, 4), 256, 0, stream>>>(Qc, Weffc, out + 16777216, 256, 1024, 1024,
                                                262144, 1048576, 262144, nullptr);
}

// Round 3
// 465.500 us; speedup vs baseline: 1.7424x; 1.1639x over previous
//
#include <hip/hip_runtime.h>
#include <cstdint>

typedef unsigned int u32;
typedef unsigned short u16;
typedef float fx4 __attribute__((ext_vector_type(4)));
typedef __bf16 bfx8 __attribute__((ext_vector_type(8)));

// ---------- helpers ----------
__device__ __forceinline__ u16 f2bf(float f) {
  u32 u = __builtin_bit_cast(u32, f);
  u32 r = (u + 0x7fffu + ((u >> 16) & 1u)) >> 16;  // RNE
  return (u16)r;
}
__device__ __forceinline__ float bf2f(u16 v) {
  return __builtin_bit_cast(float, (u32)v << 16);
}
// async global->LDS, 16B per lane (gfx950). LDS dest = wave-uniform base + lane*16.
__device__ __forceinline__ void async_copy16(const void* g, void* l) {
  auto gp = reinterpret_cast<__attribute__((address_space(1))) void*>((uintptr_t)g);
  auto lp = reinterpret_cast<__attribute__((address_space(3))) void*>((uintptr_t)l);
  __builtin_amdgcn_global_load_lds(gp, lp, 16, 0, 0);
}

// ---------- fp32 -> bf16 conversion of x, c, 8 weights ----------
__global__ __launch_bounds__(256) void cvt_all(
    const float* __restrict__ x, const float* __restrict__ c,
    const float* __restrict__ w0, const float* __restrict__ w1,
    const float* __restrict__ w2, const float* __restrict__ w3,
    const float* __restrict__ w4, const float* __restrict__ w5,
    const float* __restrict__ w6, const float* __restrict__ w7,
    u16* __restrict__ xb, u16* __restrict__ cb, u16* __restrict__ wb) {
  const int i = blockIdx.x * 256 + threadIdx.x;  // float4 index
  const float* src;
  u16* dst;
  size_t off;
  if (i < 4194304) {            // x: 16777216 floats
    src = x; dst = xb; off = (size_t)i;
  } else if (i < 4456448) {     // c: 1048576 floats
    src = c; dst = cb; off = (size_t)(i - 4194304);
  } else {                      // 8 weights, 1048576 floats each
    const int r = i - 4456448;
    const int wsel = r >> 18;
    off = (size_t)(r & 262143);
    switch (wsel) {
      case 0: src = w0; break; case 1: src = w1; break;
      case 2: src = w2; break; case 3: src = w3; break;
      case 4: src = w4; break; case 5: src = w5; break;
      case 6: src = w6; break; default: src = w7; break;
    }
    dst = wb + (size_t)wsel * 1048576;
  }
  const fx4 v = *(const fx4*)(src + off * 4);
  uint2 o;
  o.x = (u32)f2bf(v[0]) | ((u32)f2bf(v[1]) << 16);
  o.y = (u32)f2bf(v[2]) | ((u32)f2bf(v[3]) << 16);
  *(uint2*)(dst + off * 4) = o;
}

// ---------- shared GEMM core: 128x128 tile, K=1024, row stride 1024 ----------
// acc[mi][ni] over wave 64x64 sub-tile; As/Bs are 128x64 bf16 LDS tiles.
__device__ __forceinline__ void gemm_core_k1024(
    const u16* __restrict__ A, const u16* __restrict__ Bw,
    long rowBase, long colBase, u16* As, u16* Bs, fx4 (&acc)[4][4]) {
  const int t = threadIdx.x;
  const int lane = t & 63;
  const int lr = lane & 15;
  const int quad = lane >> 4;
  const int w = t >> 6;
  const int m0 = (w & 1) * 64;
  const int n0 = (w >> 1) * 64;
  const int f0 = t * 8;

  for (int k0 = 0; k0 < 1024; k0 += 64) {
#pragma unroll
    for (int r = 0; r < 4; ++r) {
      const int f = f0 + r * 2048;        // flat bf16 index in 128x64 tile
      const int row = f >> 6;
      const int col = f & 63;
      async_copy16(A + (rowBase + row) * 1024 + (k0 + col), &As[f]);
      async_copy16(Bw + (colBase + row) * 1024 + (k0 + col), &Bs[f]);
    }
    __syncthreads();
#pragma unroll
    for (int ks = 0; ks < 2; ++ks) {
      bfx8 af[4], bfr[4];
#pragma unroll
      for (int i = 0; i < 4; ++i)
        af[i] = *(const bfx8*)&As[(m0 + i * 16 + lr) * 64 + ks * 32 + quad * 8];
#pragma unroll
      for (int i = 0; i < 4; ++i)
        bfr[i] = *(const bfx8*)&Bs[(n0 + i * 16 + lr) * 64 + ks * 32 + quad * 8];
#pragma unroll
      for (int mi = 0; mi < 4; ++mi)
#pragma unroll
        for (int ni = 0; ni < 4; ++ni)
          acc[mi][ni] =
              __builtin_amdgcn_mfma_f32_16x16x32_bf16(af[mi], bfr[ni], acc[mi][ni], 0, 0, 0);
    }
    __syncthreads();
  }
}

// ---------- fused projections: all 6 QKV GEMMs in one dispatch ----------
// grid (24, 136): y<128 -> x-stream row tiles, y>=128 -> c-stream row tiles.
// cols 0..3071 = [Wq | Wk | Wv]; epilogue: l2norm (q,k) or v-scale (v), bf16 out.
__global__ __launch_bounds__(256) void proj_fused(
    const u16* __restrict__ Xb, const u16* __restrict__ Cb, const u16* __restrict__ Wb,
    u16* __restrict__ Qx, u16* __restrict__ Kx, u16* __restrict__ Vx,
    u16* __restrict__ Qc, u16* __restrict__ Kc, u16* __restrict__ Vc,
    const float* __restrict__ nc) {
  __shared__ __align__(16) u16 As[128 * 64];
  __shared__ __align__(16) u16 Bs[128 * 64];
  const bool isC = blockIdx.y >= 128;
  const u16* A = isC ? Cb : Xb;
  const u16* Bw = Wb + (isC ? 3145728 : 0);  // c-stream weights at +3*1024*1024
  const long rowBase = (long)(isC ? blockIdx.y - 128 : blockIdx.y) * 128;
  const long colBase = (long)blockIdx.x * 128;

  fx4 acc[4][4] = {};
  gemm_core_k1024(A, Bw, rowBase, colBase, As, Bs, acc);

  const int t = threadIdx.x;
  const int lane = t & 63;
  const int lr = lane & 15;
  const int quad = lane >> 4;
  const int w = t >> 6;
  const int m0 = (w & 1) * 64;
  const int n0 = (w >> 1) * 64;

  const long col0 = colBase + n0;        // 64-aligned, wave covers one head segment
  const int col64 = (int)(col0 >> 6);    // 0..47
  const int sel = col64 >> 4;            // 0=q, 1=k, 2=v
  const int h = col64 & 15;
  const int lcolBase = (int)(col0 & 1023);
  u16* dst;
  if (sel == 0) dst = isC ? Qc : Qx;
  else if (sel == 1) dst = isC ? Kc : Kx;
  else dst = isC ? Vc : Vx;

  if (sel < 2) {
    // per-row l2norm over this wave's 64 columns
#pragma unroll
    for (int mi = 0; mi < 4; ++mi) {
      float ss[4] = {0.f, 0.f, 0.f, 0.f};
#pragma unroll
      for (int ni = 0; ni < 4; ++ni)
#pragma unroll
        for (int r = 0; r < 4; ++r) ss[r] += acc[mi][ni][r] * acc[mi][ni][r];
#pragma unroll
      for (int off = 1; off < 16; off <<= 1)
#pragma unroll
        for (int r = 0; r < 4; ++r) ss[r] += __shfl_xor(ss[r], off, 64);
      float sc[4];
#pragma unroll
      for (int r = 0; r < 4; ++r) sc[r] = 1.f / fmaxf(sqrtf(ss[r]), 1e-12f);
#pragma unroll
      for (int ni = 0; ni < 4; ++ni) {
        const long col = lcolBase + ni * 16 + lr;
#pragma unroll
        for (int r = 0; r < 4; ++r) {
          const long row = rowBase + m0 + mi * 16 + quad * 4 + r;
          dst[row * 1024 + col] = f2bf(acc[mi][ni][r] * sc[r]);
        }
      }
    }
  } else {
    // v-scale: 4352^(-sigmoid(nc[h])), ln(4352) = 8.3783908
    const float s = __expf(-8.3783908f / (1.f + __expf(-nc[h])));
#pragma unroll
    for (int mi = 0; mi < 4; ++mi)
#pragma unroll
      for (int ni = 0; ni < 4; ++ni) {
        const long col = lcolBase + ni * 16 + lr;
#pragma unroll
        for (int r = 0; r < 4; ++r) {
          const long row = rowBase + m0 + mi * 16 + quad * 4 + r;
          dst[row * 1024 + col] = f2bf(acc[mi][ni][r] * s);
        }
      }
  }
}

// ---------- fused output GEMMs: out = q @ Weff[b]^T for x and c streams ----------
// grid (8, 136): y -> (b = y/34, local = y%34); local<32 -> x rows, else c rows.
__global__ __launch_bounds__(256) void out_fused(
    const u16* __restrict__ Qx, const u16* __restrict__ Qc,
    const u16* __restrict__ Wex, const u16* __restrict__ Wec,
    float* __restrict__ out) {
  __shared__ __align__(16) u16 As[128 * 64];
  __shared__ __align__(16) u16 Bs[128 * 64];
  const int yt = blockIdx.y;
  const int b = yt / 34;
  const int local = yt - b * 34;
  const bool isC = local >= 32;
  const u16* A;
  const u16* Bw;
  float* C;
  long rowBase;
  if (!isC) {
    A = Qx + (size_t)b * 4194304;
    Bw = Wex + (size_t)b * 1048576;
    C = out + (size_t)b * 4194304;
    rowBase = (long)local * 128;
  } else {
    A = Qc + (size_t)b * 262144;
    Bw = Wec + (size_t)b * 1048576;
    C = out + 16777216 + (size_t)b * 262144;
    rowBase = (long)(local - 32) * 128;
  }
  const long colBase = (long)blockIdx.x * 128;

  fx4 acc[4][4] = {};
  gemm_core_k1024(A, Bw, rowBase, colBase, As, Bs, acc);

  const int t = threadIdx.x;
  const int lane = t & 63;
  const int lr = lane & 15;
  const int quad = lane >> 4;
  const int w = t >> 6;
  const int m0 = (w & 1) * 64;
  const int n0 = (w >> 1) * 64;
#pragma unroll
  for (int mi = 0; mi < 4; ++mi)
#pragma unroll
    for (int ni = 0; ni < 4; ++ni) {
      const long col = colBase + n0 + ni * 16 + lr;
#pragma unroll
      for (int r = 0; r < 4; ++r) {
        const long row = rowBase + m0 + mi * 16 + quad * 4 + r;
        C[row * 1024 + col] = acc[mi][ni][r];
      }
    }
}

// ---------- kv partials: kv[bh][d][e] += sum_n K[n,d]*V[n,e] over 256-row split ----------
__global__ __launch_bounds__(256) void kv_partial(
    const u16* __restrict__ Kx, const u16* __restrict__ Vx,
    const u16* __restrict__ Kc, const u16* __restrict__ Vc,
    float* __restrict__ part) {
  const int split = blockIdx.x;  // 0..15: x rows, 16: c rows
  const int bh = blockIdx.y;
  const int b = bh >> 4, h = bh & 15;
  const u16* Kp;
  const u16* Vp;
  size_t rowBase;
  if (split < 16) { Kp = Kx; Vp = Vx; rowBase = (size_t)b * 4096 + (size_t)split * 256; }
  else           { Kp = Kc; Vp = Vc; rowBase = (size_t)b * 256; }

  __shared__ __align__(16) float Ks[64 * 64];
  __shared__ __align__(16) float Vs[64 * 64];
  const int t = threadIdx.x;
  const int db = (t >> 4) * 4;
  const int eb = (t & 15) * 4;
  float acc[4][4] = {};

  for (int ch = 0; ch < 4; ++ch) {
#pragma unroll
    for (int j = 0; j < 2; ++j) {
      const int u = t + 256 * j;  // 0..511 : (row, group-of-8)
      const int row = u >> 3, grp = u & 7;
      const size_t goff = (rowBase + ch * 64 + row) * 1024 + h * 64 + grp * 8;
      const uint4 kq = *(const uint4*)(Kp + goff);
      const uint4 vq = *(const uint4*)(Vp + goff);
      float* kd = &Ks[row * 64 + grp * 8];
      float* vd = &Vs[row * 64 + grp * 8];
      kd[0] = bf2f((u16)(kq.x & 0xffff)); kd[1] = bf2f((u16)(kq.x >> 16));
      kd[2] = bf2f((u16)(kq.y & 0xffff)); kd[3] = bf2f((u16)(kq.y >> 16));
      kd[4] = bf2f((u16)(kq.z & 0xffff)); kd[5] = bf2f((u16)(kq.z >> 16));
      kd[6] = bf2f((u16)(kq.w & 0xffff)); kd[7] = bf2f((u16)(kq.w >> 16));
      vd[0] = bf2f((u16)(vq.x & 0xffff)); vd[1] = bf2f((u16)(vq.x >> 16));
      vd[2] = bf2f((u16)(vq.y & 0xffff)); vd[3] = bf2f((u16)(vq.y >> 16));
      vd[4] = bf2f((u16)(vq.z & 0xffff)); vd[5] = bf2f((u16)(vq.z >> 16));
      vd[6] = bf2f((u16)(vq.w & 0xffff)); vd[7] = bf2f((u16)(vq.w >> 16));
    }
    __syncthreads();
#pragma unroll 4
    for (int n = 0; n < 64; ++n) {
      const fx4 kd = *(const fx4*)&Ks[n * 64 + db];
      const fx4 ve = *(const fx4*)&Vs[n * 64 + eb];
#pragma unroll
      for (int i = 0; i < 4; ++i)
#pragma unroll
        for (int j = 0; j < 4; ++j)
          acc[i][j] += kd[i] * ve[j];
    }
    __syncthreads();
  }
  float* pp = part + ((size_t)bh * 17 + split) * 4096;
#pragma unroll
  for (int i = 0; i < 4; ++i)
#pragma unroll
    for (int j = 0; j < 4; ++j)
      pp[(db + i) * 64 + (eb + j)] = acc[i][j];
}

__global__ __launch_bounds__(256) void kv_reduce(const float* __restrict__ part,
                                                 float* __restrict__ kv) {
  const int i = blockIdx.x * 256 + threadIdx.x;  // 64*4096
  const int bh = i >> 12;
  const int de = i & 4095;
  float s = 0.f;
#pragma unroll
  for (int sp = 0; sp < 17; ++sp) s += part[((size_t)bh * 17 + sp) * 4096 + de];
  kv[i] = s;
}

// ---------- Weff[b][o, h*64+d] = sum_e Wo[o, h*64+e] * kv[b,h][d,e]  (bf16 out) ----------
// grid: (o-tile 0..15, bh 0..63, stream 0..1), block 256
__global__ __launch_bounds__(256) void weff_build(
    const u16* __restrict__ WoX, const u16* __restrict__ WoC,
    const float* __restrict__ kvb, u16* __restrict__ WeffX, u16* __restrict__ WeffC) {
  const int ot = blockIdx.x;
  const int bh = blockIdx.y;
  const int b = bh >> 4, h = bh & 15;
  const u16* Wo = blockIdx.z ? WoC : WoX;
  u16* outp = (blockIdx.z ? WeffC : WeffX) + (size_t)b * 1048576;

  __shared__ __align__(16) float kvT[64 * 64];  // [e][d]
  __shared__ __align__(16) float WoT[64 * 64];  // [e][o_local]
  const int t = threadIdx.x;
#pragma unroll
  for (int j = 0; j < 4; ++j) {
    const int idx = (t + 256 * j) * 4;  // flat = d*64+e
    const fx4 v = *(const fx4*)&kvb[(size_t)bh * 4096 + idx];
    const int d = idx >> 6;
    const int e0 = idx & 63;
#pragma unroll
    for (int k = 0; k < 4; ++k) kvT[(e0 + k) * 64 + d] = v[k];
  }
#pragma unroll
  for (int j = 0; j < 2; ++j) {
    const int u = t + 256 * j;  // 512 groups of 8 bf16
    const int row = u >> 3;     // o_local
    const int e0 = (u & 7) * 8;
    const uint4 q = *(const uint4*)&Wo[(size_t)(ot * 64 + row) * 1024 + h * 64 + e0];
    WoT[(e0 + 0) * 64 + row] = bf2f((u16)(q.x & 0xffff));
    WoT[(e0 + 1) * 64 + row] = bf2f((u16)(q.x >> 16));
    WoT[(e0 + 2) * 64 + row] = bf2f((u16)(q.y & 0xffff));
    WoT[(e0 + 3) * 64 + row] = bf2f((u16)(q.y >> 16));
    WoT[(e0 + 4) * 64 + row] = bf2f((u16)(q.z & 0xffff));
    WoT[(e0 + 5) * 64 + row] = bf2f((u16)(q.z >> 16));
    WoT[(e0 + 6) * 64 + row] = bf2f((u16)(q.w & 0xffff));
    WoT[(e0 + 7) * 64 + row] = bf2f((u16)(q.w >> 16));
  }
  __syncthreads();
  const int ob = (t >> 4) * 4;  // o_local base
  const int db = (t & 15) * 4;  // d base
  float acc[4][4] = {};
#pragma unroll 4
  for (int e = 0; e < 64; ++e) {
    const fx4 wv = *(const fx4*)&WoT[e * 64 + ob];
    const fx4 kvv = *(const fx4*)&kvT[e * 64 + db];
#pragma unroll
    for (int i = 0; i < 4; ++i)
#pragma unroll
      for (int j = 0; j < 4; ++j)
        acc[i][j] += wv[i] * kvv[j];
  }
#pragma unroll
  for (int i = 0; i < 4; ++i)
#pragma unroll
    for (int j = 0; j < 4; ++j)
      outp[(size_t)(ot * 64 + ob + i) * 1024 + h * 64 + db + j] = f2bf(acc[i][j]);
}

// ---------- launch ----------
extern "C" void kernel_launch(void* const* d_in, const int* in_sizes, int n_in,
                              void* d_out, int out_size, void* d_ws, size_t ws_size,
                              hipStream_t stream) {
  (void)in_sizes; (void)n_in; (void)out_size; (void)ws_size;
  const float* x = (const float*)d_in[0];
  const float* c = (const float*)d_in[1];
  const float* nc = (const float*)d_in[10];
  float* out = (float*)d_out;
  char* ws = (char*)d_ws;

  // workspace layout (bytes). total = 195,035,136
  u16* Xb = (u16*)(ws + 0);                 // 33,554,432
  u16* Cb = (u16*)(ws + 33554432);          //  2,097,152
  u16* Wb = (u16*)(ws + 35651584);          // 16,777,216 (8 weights bf16)
  u16* Qx = (u16*)(ws + 52428800);          // 33,554,432
  u16* Kx = (u16*)(ws + 85983232);          // 33,554,432
  u16* Vx = (u16*)(ws + 119537664);         // 33,554,432
  u16* Qc = (u16*)(ws + 153092096);         //  2,097,152
  u16* Kc = (u16*)(ws + 155189248);         //  2,097,152
  u16* Vc = (u16*)(ws + 157286400);         //  2,097,152
  float* part = (float*)(ws + 159383552);   // 17,825,792
  float* kvb = (float*)(ws + 177209344);    //  1,048,576
  u16* Weffx = (u16*)(ws + 178257920);      //  8,388,608
  u16* Weffc = (u16*)(ws + 186646528);      //  8,388,608

  cvt_all<<<25600, 256, 0, stream>>>(
      x, c, (const float*)d_in[2], (const float*)d_in[3], (const float*)d_in[4],
      (const float*)d_in[5], (const float*)d_in[6], (const float*)d_in[7],
      (const float*)d_in[8], (const float*)d_in[9], Xb, Cb, Wb);

  // all 6 QKV projections in one dispatch
  proj_fused<<<dim3(24, 136), 256, 0, stream>>>(Xb, Cb, Wb, Qx, Kx, Vx, Qc, Kc, Vc, nc);
  // kv = k^T v over concatenated sequence (16 x-splits + 1 c-split), then reduce
  kv_partial<<<dim3(17, 64), 256, 0, stream>>>(Kx, Vx, Kc, Vc, part);
  kv_reduce<<<1024, 256, 0, stream>>>(part, kvb);
  // fold kv into output projections: Weff[b] = blockdiag(kv) applied to Wo
  weff_build<<<dim3(16, 64, 2), 256, 0, stream>>>(Wb + 6 * 1048576, Wb + 7 * 1048576,
                                                  kvb, Weffx, Weffc);
  // both output GEMMs in one dispatch, straight into d_out (fp32)
  out_fused<<<dim3(8, 136), 256, 0, stream>>>(Qx, Qc, Weffx, Weffc, out);
}

// Round 4
// 439.444 us; speedup vs baseline: 1.8457x; 1.0593x over previous
//
#include <hip/hip_runtime.h>
#include <cstdint>

typedef unsigned int u32;
typedef unsigned short u16;
typedef float fx4 __attribute__((ext_vector_type(4)));
typedef __bf16 bfx8 __attribute__((ext_vector_type(8)));

// ---------- helpers ----------
__device__ __forceinline__ u16 f2bf(float f) {
  u32 u = __builtin_bit_cast(u32, f);
  u32 r = (u + 0x7fffu + ((u >> 16) & 1u)) >> 16;  // RNE
  return (u16)r;
}
__device__ __forceinline__ float bf2f(u16 v) {
  return __builtin_bit_cast(float, (u32)v << 16);
}
// async global->LDS, 16B per lane (gfx950). LDS dest = wave-uniform base + lane*16.
__device__ __forceinline__ void async_copy16(const void* g, void* l) {
  auto gp = reinterpret_cast<__attribute__((address_space(1))) void*>((uintptr_t)g);
  auto lp = reinterpret_cast<__attribute__((address_space(3))) void*>((uintptr_t)l);
  __builtin_amdgcn_global_load_lds(gp, lp, 16, 0, 0);
}

// ---------- fp32 -> bf16 conversion of x, c, 8 weights ----------
__global__ __launch_bounds__(256) void cvt_all(
    const float* __restrict__ x, const float* __restrict__ c,
    const float* __restrict__ w0, const float* __restrict__ w1,
    const float* __restrict__ w2, const float* __restrict__ w3,
    const float* __restrict__ w4, const float* __restrict__ w5,
    const float* __restrict__ w6, const float* __restrict__ w7,
    u16* __restrict__ xb, u16* __restrict__ cb, u16* __restrict__ wb) {
  const int i = blockIdx.x * 256 + threadIdx.x;  // float4 index
  const float* src;
  u16* dst;
  size_t off;
  if (i < 4194304) {            // x: 16777216 floats
    src = x; dst = xb; off = (size_t)i;
  } else if (i < 4456448) {     // c: 1048576 floats
    src = c; dst = cb; off = (size_t)(i - 4194304);
  } else {                      // 8 weights, 1048576 floats each
    const int r = i - 4456448;
    const int wsel = r >> 18;
    off = (size_t)(r & 262143);
    switch (wsel) {
      case 0: src = w0; break; case 1: src = w1; break;
      case 2: src = w2; break; case 3: src = w3; break;
      case 4: src = w4; break; case 5: src = w5; break;
      case 6: src = w6; break; default: src = w7; break;
    }
    dst = wb + (size_t)wsel * 1048576;
  }
  const fx4 v = *(const fx4*)(src + off * 4);
  uint2 o;
  o.x = (u32)f2bf(v[0]) | ((u32)f2bf(v[1]) << 16);
  o.y = (u32)f2bf(v[2]) | ((u32)f2bf(v[3]) << 16);
  *(uint2*)(dst + off * 4) = o;
}

// ---------- shared GEMM core: 128x128 tile, K=1024, row stride 1024 ----------
// XOR-swizzled LDS tiles: store-group g holds global group g ^ (row&7), so each
// ds_read_b128 spreads 64 lanes over all 8 bank-sets (conflict-free) while the
// global_load_lds staging keeps its mandatory lane-contiguous LDS layout.
__device__ __forceinline__ void gemm_core_k1024(
    const u16* __restrict__ A, const u16* __restrict__ Bw,
    long rowBase, long colBase, u16* As, u16* Bs, fx4 (&acc)[4][4]) {
  const int t = threadIdx.x;
  const int lane = t & 63;
  const int lr = lane & 15;
  const int quad = lane >> 4;
  const int sw = lr & 7;               // read-side swizzle key
  const int w = t >> 6;
  const int m0 = (w & 1) * 64;
  const int n0 = (w >> 1) * 64;
  const int f0 = t * 8;

  for (int k0 = 0; k0 < 1024; k0 += 64) {
#pragma unroll
    for (int r = 0; r < 4; ++r) {
      const int f = f0 + r * 2048;        // flat bf16 index in 128x64 tile
      const int row = f >> 6;
      const int gst = (f >> 3) & 7;       // stored 16B-group within row
      const int col = ((gst ^ (row & 7)) << 3);  // fetch the swizzled source group
      async_copy16(A + (rowBase + row) * 1024 + (k0 + col), &As[f]);
      async_copy16(Bw + (colBase + row) * 1024 + (k0 + col), &Bs[f]);
    }
    __syncthreads();
#pragma unroll
    for (int ks = 0; ks < 2; ++ks) {
      bfx8 af[4], bfr[4];
      const int g = ((ks * 4 + quad) ^ sw) << 3;  // swizzled group offset (u16)
#pragma unroll
      for (int i = 0; i < 4; ++i)
        af[i] = *(const bfx8*)&As[(m0 + i * 16 + lr) * 64 + g];
#pragma unroll
      for (int i = 0; i < 4; ++i)
        bfr[i] = *(const bfx8*)&Bs[(n0 + i * 16 + lr) * 64 + g];
#pragma unroll
      for (int mi = 0; mi < 4; ++mi)
#pragma unroll
        for (int ni = 0; ni < 4; ++ni)
          acc[mi][ni] =
              __builtin_amdgcn_mfma_f32_16x16x32_bf16(af[mi], bfr[ni], acc[mi][ni], 0, 0, 0);
    }
    __syncthreads();
  }
}

// ---------- fused projections: all 6 QKV GEMMs in one dispatch ----------
// grid (24, 136): y<128 -> x-stream row tiles, y>=128 -> c-stream row tiles.
// cols 0..3071 = [Wq | Wk | Wv]; epilogue: l2norm (q,k) or v-scale (v), bf16 out.
__global__ __launch_bounds__(256) void proj_fused(
    const u16* __restrict__ Xb, const u16* __restrict__ Cb, const u16* __restrict__ Wb,
    u16* __restrict__ Qx, u16* __restrict__ Kx, u16* __restrict__ Vx,
    u16* __restrict__ Qc, u16* __restrict__ Kc, u16* __restrict__ Vc,
    const float* __restrict__ nc) {
  __shared__ __align__(16) u16 As[128 * 64];
  __shared__ __align__(16) u16 Bs[128 * 64];
  const bool isC = blockIdx.y >= 128;
  const u16* A = isC ? Cb : Xb;
  const u16* Bw = Wb + (isC ? 3145728 : 0);  // c-stream weights at +3*1024*1024
  const long rowBase = (long)(isC ? blockIdx.y - 128 : blockIdx.y) * 128;
  const long colBase = (long)blockIdx.x * 128;

  fx4 acc[4][4] = {};
  gemm_core_k1024(A, Bw, rowBase, colBase, As, Bs, acc);

  const int t = threadIdx.x;
  const int lane = t & 63;
  const int lr = lane & 15;
  const int quad = lane >> 4;
  const int w = t >> 6;
  const int m0 = (w & 1) * 64;
  const int n0 = (w >> 1) * 64;

  const long col0 = colBase + n0;        // 64-aligned, wave covers one head segment
  const int col64 = (int)(col0 >> 6);    // 0..47
  const int sel = col64 >> 4;            // 0=q, 1=k, 2=v
  const int h = col64 & 15;
  const int lcolBase = (int)(col0 & 1023);
  u16* dst;
  if (sel == 0) dst = isC ? Qc : Qx;
  else if (sel == 1) dst = isC ? Kc : Kx;
  else dst = isC ? Vc : Vx;

  if (sel < 2) {
    // per-row l2norm over this wave's 64 columns
#pragma unroll
    for (int mi = 0; mi < 4; ++mi) {
      float ss[4] = {0.f, 0.f, 0.f, 0.f};
#pragma unroll
      for (int ni = 0; ni < 4; ++ni)
#pragma unroll
        for (int r = 0; r < 4; ++r) ss[r] += acc[mi][ni][r] * acc[mi][ni][r];
#pragma unroll
      for (int off = 1; off < 16; off <<= 1)
#pragma unroll
        for (int r = 0; r < 4; ++r) ss[r] += __shfl_xor(ss[r], off, 64);
      float sc[4];
#pragma unroll
      for (int r = 0; r < 4; ++r) sc[r] = 1.f / fmaxf(sqrtf(ss[r]), 1e-12f);
#pragma unroll
      for (int ni = 0; ni < 4; ++ni) {
        const long col = lcolBase + ni * 16 + lr;
#pragma unroll
        for (int r = 0; r < 4; ++r) {
          const long row = rowBase + m0 + mi * 16 + quad * 4 + r;
          dst[row * 1024 + col] = f2bf(acc[mi][ni][r] * sc[r]);
        }
      }
    }
  } else {
    // v-scale: 4352^(-sigmoid(nc[h])), ln(4352) = 8.3783908
    const float s = __expf(-8.3783908f / (1.f + __expf(-nc[h])));
#pragma unroll
    for (int mi = 0; mi < 4; ++mi)
#pragma unroll
      for (int ni = 0; ni < 4; ++ni) {
        const long col = lcolBase + ni * 16 + lr;
#pragma unroll
        for (int r = 0; r < 4; ++r) {
          const long row = rowBase + m0 + mi * 16 + quad * 4 + r;
          dst[row * 1024 + col] = f2bf(acc[mi][ni][r] * s);
        }
      }
  }
}

// ---------- fused output GEMMs: out = q @ Weff[b]^T for x and c streams ----------
// grid (8, 136): y -> (b = y/34, local = y%34); local<32 -> x rows, else c rows.
__global__ __launch_bounds__(256) void out_fused(
    const u16* __restrict__ Qx, const u16* __restrict__ Qc,
    const u16* __restrict__ Wex, const u16* __restrict__ Wec,
    float* __restrict__ out) {
  __shared__ __align__(16) u16 As[128 * 64];
  __shared__ __align__(16) u16 Bs[128 * 64];
  const int yt = blockIdx.y;
  const int b = yt / 34;
  const int local = yt - b * 34;
  const bool isC = local >= 32;
  const u16* A;
  const u16* Bw;
  float* C;
  long rowBase;
  if (!isC) {
    A = Qx + (size_t)b * 4194304;
    Bw = Wex + (size_t)b * 1048576;
    C = out + (size_t)b * 4194304;
    rowBase = (long)local * 128;
  } else {
    A = Qc + (size_t)b * 262144;
    Bw = Wec + (size_t)b * 1048576;
    C = out + 16777216 + (size_t)b * 262144;
    rowBase = (long)(local - 32) * 128;
  }
  const long colBase = (long)blockIdx.x * 128;

  fx4 acc[4][4] = {};
  gemm_core_k1024(A, Bw, rowBase, colBase, As, Bs, acc);

  const int t = threadIdx.x;
  const int lane = t & 63;
  const int lr = lane & 15;
  const int quad = lane >> 4;
  const int w = t >> 6;
  const int m0 = (w & 1) * 64;
  const int n0 = (w >> 1) * 64;
#pragma unroll
  for (int mi = 0; mi < 4; ++mi)
#pragma unroll
    for (int ni = 0; ni < 4; ++ni) {
      const long col = colBase + n0 + ni * 16 + lr;
#pragma unroll
      for (int r = 0; r < 4; ++r) {
        const long row = rowBase + m0 + mi * 16 + quad * 4 + r;
        C[row * 1024 + col] = acc[mi][ni][r];
      }
    }
}

// ---------- kv partials: kv[bh][d][e] += sum_n K[n,d]*V[n,e] over 256-row split ----------
__global__ __launch_bounds__(256) void kv_partial(
    const u16* __restrict__ Kx, const u16* __restrict__ Vx,
    const u16* __restrict__ Kc, const u16* __restrict__ Vc,
    float* __restrict__ part) {
  const int split = blockIdx.x;  // 0..15: x rows, 16: c rows
  const int bh = blockIdx.y;
  const int b = bh >> 4, h = bh & 15;
  const u16* Kp;
  const u16* Vp;
  size_t rowBase;
  if (split < 16) { Kp = Kx; Vp = Vx; rowBase = (size_t)b * 4096 + (size_t)split * 256; }
  else           { Kp = Kc; Vp = Vc; rowBase = (size_t)b * 256; }

  __shared__ __align__(16) float Ks[64 * 64];
  __shared__ __align__(16) float Vs[64 * 64];
  const int t = threadIdx.x;
  const int db = (t >> 4) * 4;
  const int eb = (t & 15) * 4;
  float acc[4][4] = {};

  for (int ch = 0; ch < 4; ++ch) {
#pragma unroll
    for (int j = 0; j < 2; ++j) {
      const int u = t + 256 * j;  // 0..511 : (row, group-of-8)
      const int row = u >> 3, grp = u & 7;
      const size_t goff = (rowBase + ch * 64 + row) * 1024 + h * 64 + grp * 8;
      const uint4 kq = *(const uint4*)(Kp + goff);
      const uint4 vq = *(const uint4*)(Vp + goff);
      float* kd = &Ks[row * 64 + grp * 8];
      float* vd = &Vs[row * 64 + grp * 8];
      kd[0] = bf2f((u16)(kq.x & 0xffff)); kd[1] = bf2f((u16)(kq.x >> 16));
      kd[2] = bf2f((u16)(kq.y & 0xffff)); kd[3] = bf2f((u16)(kq.y >> 16));
      kd[4] = bf2f((u16)(kq.z & 0xffff)); kd[5] = bf2f((u16)(kq.z >> 16));
      kd[6] = bf2f((u16)(kq.w & 0xffff)); kd[7] = bf2f((u16)(kq.w >> 16));
      vd[0] = bf2f((u16)(vq.x & 0xffff)); vd[1] = bf2f((u16)(vq.x >> 16));
      vd[2] = bf2f((u16)(vq.y & 0xffff)); vd[3] = bf2f((u16)(vq.y >> 16));
      vd[4] = bf2f((u16)(vq.z & 0xffff)); vd[5] = bf2f((u16)(vq.z >> 16));
      vd[6] = bf2f((u16)(vq.w & 0xffff)); vd[7] = bf2f((u16)(vq.w >> 16));
    }
    __syncthreads();
#pragma unroll 4
    for (int n = 0; n < 64; ++n) {
      const fx4 kd = *(const fx4*)&Ks[n * 64 + db];
      const fx4 ve = *(const fx4*)&Vs[n * 64 + eb];
#pragma unroll
      for (int i = 0; i < 4; ++i)
#pragma unroll
        for (int j = 0; j < 4; ++j)
          acc[i][j] += kd[i] * ve[j];
    }
    __syncthreads();
  }
  float* pp = part + ((size_t)bh * 17 + split) * 4096;
#pragma unroll
  for (int i = 0; i < 4; ++i)
#pragma unroll
    for (int j = 0; j < 4; ++j)
      pp[(db + i) * 64 + (eb + j)] = acc[i][j];
}

__global__ __launch_bounds__(256) void kv_reduce(const float* __restrict__ part,
                                                 float* __restrict__ kv) {
  const int i = blockIdx.x * 256 + threadIdx.x;  // 64*4096
  const int bh = i >> 12;
  const int de = i & 4095;
  float s = 0.f;
#pragma unroll
  for (int sp = 0; sp < 17; ++sp) s += part[((size_t)bh * 17 + sp) * 4096 + de];
  kv[i] = s;
}

// ---------- Weff[b][o, h*64+d] = sum_e Wo[o, h*64+e] * kv[b,h][d,e]  (bf16 out) ----------
// grid: (o-tile 0..15, bh 0..63, stream 0..1), block 256
__global__ __launch_bounds__(256) void weff_build(
    const u16* __restrict__ WoX, const u16* __restrict__ WoC,
    const float* __restrict__ kvb, u16* __restrict__ WeffX, u16* __restrict__ WeffC) {
  const int ot = blockIdx.x;
  const int bh = blockIdx.y;
  const int b = bh >> 4, h = bh & 15;
  const u16* Wo = blockIdx.z ? WoC : WoX;
  u16* outp = (blockIdx.z ? WeffC : WeffX) + (size_t)b * 1048576;

  __shared__ __align__(16) float kvT[64 * 64];  // [e][d]
  __shared__ __align__(16) float WoT[64 * 64];  // [e][o_local]
  const int t = threadIdx.x;
#pragma unroll
  for (int j = 0; j < 4; ++j) {
    const int idx = (t + 256 * j) * 4;  // flat = d*64+e
    const fx4 v = *(const fx4*)&kvb[(size_t)bh * 4096 + idx];
    const int d = idx >> 6;
    const int e0 = idx & 63;
#pragma unroll
    for (int k = 0; k < 4; ++k) kvT[(e0 + k) * 64 + d] = v[k];
  }
#pragma unroll
  for (int j = 0; j < 2; ++j) {
    const int u = t + 256 * j;  // 512 groups of 8 bf16
    const int row = u >> 3;     // o_local
    const int e0 = (u & 7) * 8;
    const uint4 q = *(const uint4*)&Wo[(size_t)(ot * 64 + row) * 1024 + h * 64 + e0];
    WoT[(e0 + 0) * 64 + row] = bf2f((u16)(q.x & 0xffff));
    WoT[(e0 + 1) * 64 + row] = bf2f((u16)(q.x >> 16));
    WoT[(e0 + 2) * 64 + row] = bf2f((u16)(q.y & 0xffff));
    WoT[(e0 + 3) * 64 + row] = bf2f((u16)(q.y >> 16));
    WoT[(e0 + 4) * 64 + row] = bf2f((u16)(q.z & 0xffff));
    WoT[(e0 + 5) * 64 + row] = bf2f((u16)(q.z >> 16));
    WoT[(e0 + 6) * 64 + row] = bf2f((u16)(q.w & 0xffff));
    WoT[(e0 + 7) * 64 + row] = bf2f((u16)(q.w >> 16));
  }
  __syncthreads();
  const int ob = (t >> 4) * 4;  // o_local base
  const int db = (t & 15) * 4;  // d base
  float acc[4][4] = {};
#pragma unroll 4
  for (int e = 0; e < 64; ++e) {
    const fx4 wv = *(const fx4*)&WoT[e * 64 + ob];
    const fx4 kvv = *(const fx4*)&kvT[e * 64 + db];
#pragma unroll
    for (int i = 0; i < 4; ++i)
#pragma unroll
      for (int j = 0; j < 4; ++j)
        acc[i][j] += wv[i] * kvv[j];
  }
#pragma unroll
  for (int i = 0; i < 4; ++i)
#pragma unroll
    for (int j = 0; j < 4; ++j)
      outp[(size_t)(ot * 64 + ob + i) * 1024 + h * 64 + db + j] = f2bf(acc[i][j]);
}

// ---------- launch ----------
extern "C" void kernel_launch(void* const* d_in, const int* in_sizes, int n_in,
                              void* d_out, int out_size, void* d_ws, size_t ws_size,
                              hipStream_t stream) {
  (void)in_sizes; (void)n_in; (void)out_size; (void)ws_size;
  const float* x = (const float*)d_in[0];
  const float* c = (const float*)d_in[1];
  const float* nc = (const float*)d_in[10];
  float* out = (float*)d_out;
  char* ws = (char*)d_ws;

  // workspace layout (bytes). total = 195,035,136
  u16* Xb = (u16*)(ws + 0);                 // 33,554,432
  u16* Cb = (u16*)(ws + 33554432);          //  2,097,152
  u16* Wb = (u16*)(ws + 35651584);          // 16,777,216 (8 weights bf16)
  u16* Qx = (u16*)(ws + 52428800);          // 33,554,432
  u16* Kx = (u16*)(ws + 85983232);          // 33,554,432
  u16* Vx = (u16*)(ws + 119537664);         // 33,554,432
  u16* Qc = (u16*)(ws + 153092096);         //  2,097,152
  u16* Kc = (u16*)(ws + 155189248);         //  2,097,152
  u16* Vc = (u16*)(ws + 157286400);         //  2,097,152
  float* part = (float*)(ws + 159383552);   // 17,825,792
  float* kvb = (float*)(ws + 177209344);    //  1,048,576
  u16* Weffx = (u16*)(ws + 178257920);      //  8,388,608
  u16* Weffc = (u16*)(ws + 186646528);      //  8,388,608

  cvt_all<<<25600, 256, 0, stream>>>(
      x, c, (const float*)d_in[2], (const float*)d_in[3], (const float*)d_in[4],
      (const float*)d_in[5], (const float*)d_in[6], (const float*)d_in[7],
      (const float*)d_in[8], (const float*)d_in[9], Xb, Cb, Wb);

  // all 6 QKV projections in one dispatch
  proj_fused<<<dim3(24, 136), 256, 0, stream>>>(Xb, Cb, Wb, Qx, Kx, Vx, Qc, Kc, Vc, nc);
  // kv = k^T v over concatenated sequence (16 x-splits + 1 c-split), then reduce
  kv_partial<<<dim3(17, 64), 256, 0, stream>>>(Kx, Vx, Kc, Vc, part);
  kv_reduce<<<1024, 256, 0, stream>>>(part, kvb);
  // fold kv into output projections: Weff[b] = blockdiag(kv) applied to Wo
  weff_build<<<dim3(16, 64, 2), 256, 0, stream>>>(Wb + 6 * 1048576, Wb + 7 * 1048576,
                                                  kvb, Weffx, Weffc);
  // both output GEMMs in one dispatch, straight into d_out (fp32)
  out_fused<<<dim3(8, 136), 256, 0, stream>>>(Qx, Qc, Weffx, Weffc, out);
}

// Round 5
// 428.122 us; speedup vs baseline: 1.8945x; 1.0264x over previous
//
#include <hip/hip_runtime.h>
#include <cstdint>

typedef unsigned int u32;
typedef unsigned short u16;
typedef float fx4 __attribute__((ext_vector_type(4)));
typedef __bf16 bfx8 __attribute__((ext_vector_type(8)));

// ---------- helpers ----------
__device__ __forceinline__ u16 f2bf(float f) {
  u32 u = __builtin_bit_cast(u32, f);
  u32 r = (u + 0x7fffu + ((u >> 16) & 1u)) >> 16;  // RNE
  return (u16)r;
}
__device__ __forceinline__ float bf2f(u16 v) {
  return __builtin_bit_cast(float, (u32)v << 16);
}
// async global->LDS, 16B per lane (gfx950). LDS dest = wave-uniform base + lane*16.
__device__ __forceinline__ void async_copy16(const void* g, void* l) {
  auto gp = reinterpret_cast<__attribute__((address_space(1))) void*>((uintptr_t)g);
  auto lp = reinterpret_cast<__attribute__((address_space(3))) void*>((uintptr_t)l);
  __builtin_amdgcn_global_load_lds(gp, lp, 16, 0, 0);
}

// ---------- fp32 -> bf16 conversion of x, c, 8 weights ----------
__global__ __launch_bounds__(256) void cvt_all(
    const float* __restrict__ x, const float* __restrict__ c,
    const float* __restrict__ w0, const float* __restrict__ w1,
    const float* __restrict__ w2, const float* __restrict__ w3,
    const float* __restrict__ w4, const float* __restrict__ w5,
    const float* __restrict__ w6, const float* __restrict__ w7,
    u16* __restrict__ xb, u16* __restrict__ cb, u16* __restrict__ wb) {
  const int i = blockIdx.x * 256 + threadIdx.x;  // float4 index
  const float* src;
  u16* dst;
  size_t off;
  if (i < 4194304) {            // x: 16777216 floats
    src = x; dst = xb; off = (size_t)i;
  } else if (i < 4456448) {     // c: 1048576 floats
    src = c; dst = cb; off = (size_t)(i - 4194304);
  } else {                      // 8 weights, 1048576 floats each
    const int r = i - 4456448;
    const int wsel = r >> 18;
    off = (size_t)(r & 262143);
    switch (wsel) {
      case 0: src = w0; break; case 1: src = w1; break;
      case 2: src = w2; break; case 3: src = w3; break;
      case 4: src = w4; break; case 5: src = w5; break;
      case 6: src = w6; break; default: src = w7; break;
    }
    dst = wb + (size_t)wsel * 1048576;
  }
  const fx4 v = *(const fx4*)(src + off * 4);
  uint2 o;
  o.x = (u32)f2bf(v[0]) | ((u32)f2bf(v[1]) << 16);
  o.y = (u32)f2bf(v[2]) | ((u32)f2bf(v[3]) << 16);
  *(uint2*)(dst + off * 4) = o;
}

// ---------- shared GEMM core: 128x128 tile, K=1024, row stride 1024 ----------
// XOR-swizzled LDS tiles (conflict-free frag reads, verified R4: conflicts -> 0).
__device__ __forceinline__ void gemm_core_k1024(
    const u16* __restrict__ A, const u16* __restrict__ Bw,
    long rowBase, long colBase, u16* As, u16* Bs, fx4 (&acc)[4][4]) {
  const int t = threadIdx.x;
  const int lane = t & 63;
  const int lr = lane & 15;
  const int quad = lane >> 4;
  const int sw = lr & 7;               // read-side swizzle key
  const int w = t >> 6;
  const int m0 = (w & 1) * 64;
  const int n0 = (w >> 1) * 64;
  const int f0 = t * 8;

  for (int k0 = 0; k0 < 1024; k0 += 64) {
#pragma unroll
    for (int r = 0; r < 4; ++r) {
      const int f = f0 + r * 2048;        // flat bf16 index in 128x64 tile
      const int row = f >> 6;
      const int gst = (f >> 3) & 7;       // stored 16B-group within row
      const int col = ((gst ^ (row & 7)) << 3);  // fetch the swizzled source group
      async_copy16(A + (rowBase + row) * 1024 + (k0 + col), &As[f]);
      async_copy16(Bw + (colBase + row) * 1024 + (k0 + col), &Bs[f]);
    }
    __syncthreads();
#pragma unroll
    for (int ks = 0; ks < 2; ++ks) {
      bfx8 af[4], bfr[4];
      const int g = ((ks * 4 + quad) ^ sw) << 3;  // swizzled group offset (u16)
#pragma unroll
      for (int i = 0; i < 4; ++i)
        af[i] = *(const bfx8*)&As[(m0 + i * 16 + lr) * 64 + g];
#pragma unroll
      for (int i = 0; i < 4; ++i)
        bfr[i] = *(const bfx8*)&Bs[(n0 + i * 16 + lr) * 64 + g];
#pragma unroll
      for (int mi = 0; mi < 4; ++mi)
#pragma unroll
        for (int ni = 0; ni < 4; ++ni)
          acc[mi][ni] =
              __builtin_amdgcn_mfma_f32_16x16x32_bf16(af[mi], bfr[ni], acc[mi][ni], 0, 0, 0);
    }
    __syncthreads();
  }
}

// ---------- fused projections: all 6 QKV GEMMs in one dispatch ----------
// grid (24, 136): y<128 -> x-stream rows, y>=128 -> c-stream rows.
// cols 0..3071 = [Wq | Wk | Wv].  Q: l2norm, row-major store.
// K: l2norm, transposed store to Kt[b,h][d][n].  V: scale, transposed to Vt.
__global__ __launch_bounds__(256) void proj_fused(
    const u16* __restrict__ Xb, const u16* __restrict__ Cb, const u16* __restrict__ Wb,
    u16* __restrict__ Qx, u16* __restrict__ Qc,
    u16* __restrict__ Kt, u16* __restrict__ Vt,
    const float* __restrict__ nc) {
  __shared__ __align__(16) u16 LDSbuf[2 * 128 * 64];
  u16* As = LDSbuf;
  u16* Bs = LDSbuf + 8192;
  const bool isC = blockIdx.y >= 128;
  const u16* A = isC ? Cb : Xb;
  const u16* Bw = Wb + (isC ? 3145728 : 0);  // c-stream weights at +3*1024*1024
  const long rowBase = (long)(isC ? blockIdx.y - 128 : blockIdx.y) * 128;
  const long colBase = (long)blockIdx.x * 128;

  fx4 acc[4][4] = {};
  gemm_core_k1024(A, Bw, rowBase, colBase, As, Bs, acc);
  // core ends with __syncthreads(): LDSbuf is reusable now.

  const int t = threadIdx.x;
  const int lane = t & 63;
  const int lr = lane & 15;
  const int quad = lane >> 4;
  const int w = t >> 6;
  const int m0 = (w & 1) * 64;
  const int n0 = (w >> 1) * 64;

  const long col0 = colBase + n0;        // 64-aligned, wave covers one head segment
  const int col64 = (int)(col0 >> 6);    // 0..47
  const int sel = col64 >> 4;            // 0=q, 1=k, 2=v  (uniform per block)
  const int h = col64 & 15;
  const int lcolBase = (int)(col0 & 1023);

  if (sel == 0) {
    // Q: per-row l2norm, row-major store (feeds out_fused A-operand)
    u16* dst = isC ? Qc : Qx;
#pragma unroll
    for (int mi = 0; mi < 4; ++mi) {
      float ss[4] = {0.f, 0.f, 0.f, 0.f};
#pragma unroll
      for (int ni = 0; ni < 4; ++ni)
#pragma unroll
        for (int r = 0; r < 4; ++r) ss[r] += acc[mi][ni][r] * acc[mi][ni][r];
#pragma unroll
      for (int off = 1; off < 16; off <<= 1)
#pragma unroll
        for (int r = 0; r < 4; ++r) ss[r] += __shfl_xor(ss[r], off, 64);
      float sc[4];
#pragma unroll
      for (int r = 0; r < 4; ++r) sc[r] = 1.f / fmaxf(sqrtf(ss[r]), 1e-12f);
#pragma unroll
      for (int ni = 0; ni < 4; ++ni) {
        const long col = lcolBase + ni * 16 + lr;
#pragma unroll
        for (int r = 0; r < 4; ++r) {
          const long row = rowBase + m0 + mi * 16 + quad * 4 + r;
          dst[row * 1024 + col] = f2bf(acc[mi][ni][r] * sc[r]);
        }
      }
    }
  } else {
    // K (l2norm) / V (scale): wave-local LDS transpose -> Kt/Vt[b,h][d][0..4352)
    u16* LT = LDSbuf + w * 4096;  // 8 KB per wave: [d][64 n] bf16, n-group ^ (d&7)
    u16* T = (sel == 1) ? Kt : Vt;
    const long R0 = rowBase + m0;
    int b, nglob0;
    if (!isC) { b = (int)(R0 >> 12); nglob0 = (int)(R0 & 4095); }
    else      { b = (int)(R0 >> 8);  nglob0 = 4096 + (int)(R0 & 255); }
    u16* Tw = T + (size_t)(b * 16 + h) * 64 * 4352;
    const float vs = __expf(-8.3783908f / (1.f + __expf(-nc[h])));  // 4352^-sigmoid

#pragma unroll
    for (int mi = 0; mi < 4; ++mi) {
      float sc[4];
      if (sel == 1) {
        float ss[4] = {0.f, 0.f, 0.f, 0.f};
#pragma unroll
        for (int ni = 0; ni < 4; ++ni)
#pragma unroll
          for (int r = 0; r < 4; ++r) ss[r] += acc[mi][ni][r] * acc[mi][ni][r];
#pragma unroll
        for (int off = 1; off < 16; off <<= 1)
#pragma unroll
          for (int r = 0; r < 4; ++r) ss[r] += __shfl_xor(ss[r], off, 64);
#pragma unroll
        for (int r = 0; r < 4; ++r) sc[r] = 1.f / fmaxf(sqrtf(ss[r]), 1e-12f);
      } else {
#pragma unroll
        for (int r = 0; r < 4; ++r) sc[r] = vs;
      }
      const int g = 2 * mi + (quad >> 1);   // n-group (n = mi*16+quad*4+r)
      const int sub = (quad & 1) * 4;       // n offset within group
#pragma unroll
      for (int ni = 0; ni < 4; ++ni) {
        const int d = ni * 16 + lr;
        uint2 o;
        o.x = (u32)f2bf(acc[mi][ni][0] * sc[0]) | ((u32)f2bf(acc[mi][ni][1] * sc[1]) << 16);
        o.y = (u32)f2bf(acc[mi][ni][2] * sc[2]) | ((u32)f2bf(acc[mi][ni][3] * sc[3]) << 16);
        *(uint2*)&LT[d * 64 + ((g ^ (d & 7)) << 3) + sub] = o;
      }
    }
    __syncthreads();  // uniform (sel uniform per block); orders LDS writes
    const int d = lane;
    u16* drow = Tw + (size_t)d * 4352 + nglob0;
#pragma unroll
    for (int j = 0; j < 8; ++j) {
      const uint4 qv = *(const uint4*)&LT[d * 64 + ((j ^ (d & 7)) << 3)];
      *(uint4*)&drow[j * 8] = qv;
    }
  }
}

// ---------- kv via MFMA: kv[bh][e][d] = sum_n K[n,d] V[n,e]  (stored transposed) ----------
// grid 64 (bh). 4 waves split K=4352 (1088 each, 17 steps of 64); LDS 4-way reduce.
__global__ __launch_bounds__(256) void kv_mfma(
    const u16* __restrict__ Kt, const u16* __restrict__ Vt, float* __restrict__ kvb) {
  __shared__ __align__(16) u16 TT[4][2][4096];  // per wave: K tile, V tile (64x64 u16)
  const int bh = blockIdx.x;
  const int t = threadIdx.x;
  const int w = t >> 6;
  const int lane = t & 63;
  const int lr = lane & 15;
  const int quad = lane >> 4;
  const u16* Ksrc = Kt + (size_t)bh * 64 * 4352;
  const u16* Vsrc = Vt + (size_t)bh * 64 * 4352;
  const int row8 = lane >> 3;
  const int gst = lane & 7;
  fx4 acc[4][4] = {};

  for (int s = 0; s < 17; ++s) {
    const int kbase = w * 1088 + s * 64;
#pragma unroll
    for (int i = 0; i < 8; ++i) {
      const int row = i * 8 + row8;
      const int col = ((gst ^ (row & 7)) << 3);
      const size_t go = (size_t)row * 4352 + kbase + col;
      async_copy16(Ksrc + go, &TT[w][0][i * 512 + lane * 8]);
      async_copy16(Vsrc + go, &TT[w][1][i * 512 + lane * 8]);
    }
    __syncthreads();
#pragma unroll
    for (int ks = 0; ks < 2; ++ks) {
      bfx8 af[4], bfr[4];
      const int g = ((ks * 4 + quad) ^ (lr & 7)) << 3;
#pragma unroll
      for (int i = 0; i < 4; ++i) af[i] = *(const bfx8*)&TT[w][0][(i * 16 + lr) * 64 + g];
#pragma unroll
      for (int i = 0; i < 4; ++i) bfr[i] = *(const bfx8*)&TT[w][1][(i * 16 + lr) * 64 + g];
#pragma unroll
      for (int mi = 0; mi < 4; ++mi)
#pragma unroll
        for (int ni = 0; ni < 4; ++ni)
          acc[mi][ni] =
              __builtin_amdgcn_mfma_f32_16x16x32_bf16(af[mi], bfr[ni], acc[mi][ni], 0, 0, 0);
    }
    __syncthreads();
  }
  // per-wave partial C^T [e][d] f32, d-group swizzled; then 4-way reduce
  float* red = (float*)&TT[0][0][0];  // 16384 f32
  float* my = red + w * 4096;
#pragma unroll
  for (int mi = 0; mi < 4; ++mi)
#pragma unroll
    for (int ni = 0; ni < 4; ++ni) {
      const int e = ni * 16 + lr;
      const int dg = mi * 4 + quad;      // d = dg*4 + r, r consecutive in acc
      *(fx4*)&my[e * 64 + ((dg ^ (e & 15)) << 2)] = acc[mi][ni];
    }
  __syncthreads();
  float* outp = kvb + (size_t)bh * 4096;
#pragma unroll
  for (int j = 0; j < 4; ++j) {
    const int L = t * 16 + j * 4;        // flat [e][d] index
    const int e = L >> 6;
    const int dg = (L >> 2) & 15;
    const int addr = e * 64 + ((dg ^ (e & 15)) << 2);
    fx4 sv = *(const fx4*)&red[addr];
    sv += *(const fx4*)&red[4096 + addr];
    sv += *(const fx4*)&red[8192 + addr];
    sv += *(const fx4*)&red[12288 + addr];
    *(fx4*)&outp[L] = sv;
  }
}

// ---------- Weff[b][o, h*64+d] = sum_e Wo[o, h*64+e] * kv[b,h][d,e]  (bf16 out) ----------
// kvb holds kv transposed: kvb[bh][e*64+d].
__global__ __launch_bounds__(256) void weff_build(
    const u16* __restrict__ WoX, const u16* __restrict__ WoC,
    const float* __restrict__ kvb, u16* __restrict__ WeffX, u16* __restrict__ WeffC) {
  const int ot = blockIdx.x;
  const int bh = blockIdx.y;
  const int b = bh >> 4, h = bh & 15;
  const u16* Wo = blockIdx.z ? WoC : WoX;
  u16* outp = (blockIdx.z ? WeffC : WeffX) + (size_t)b * 1048576;

  __shared__ __align__(16) float kvT[64 * 64];  // [e][d] = kvb layout, direct copy
  __shared__ __align__(16) float WoT[64 * 64];  // [e][o_local]
  const int t = threadIdx.x;
#pragma unroll
  for (int j = 0; j < 4; ++j) {
    const int idx = (t + 256 * j) * 4;
    *(fx4*)&kvT[idx] = *(const fx4*)&kvb[(size_t)bh * 4096 + idx];
  }
#pragma unroll
  for (int j = 0; j < 2; ++j) {
    const int u = t + 256 * j;  // 512 groups of 8 bf16
    const int row = u >> 3;     // o_local
    const int e0 = (u & 7) * 8;
    const uint4 q = *(const uint4*)&Wo[(size_t)(ot * 64 + row) * 1024 + h * 64 + e0];
    WoT[(e0 + 0) * 64 + row] = bf2f((u16)(q.x & 0xffff));
    WoT[(e0 + 1) * 64 + row] = bf2f((u16)(q.x >> 16));
    WoT[(e0 + 2) * 64 + row] = bf2f((u16)(q.y & 0xffff));
    WoT[(e0 + 3) * 64 + row] = bf2f((u16)(q.y >> 16));
    WoT[(e0 + 4) * 64 + row] = bf2f((u16)(q.z & 0xffff));
    WoT[(e0 + 5) * 64 + row] = bf2f((u16)(q.z >> 16));
    WoT[(e0 + 6) * 64 + row] = bf2f((u16)(q.w & 0xffff));
    WoT[(e0 + 7) * 64 + row] = bf2f((u16)(q.w >> 16));
  }
  __syncthreads();
  const int ob = (t >> 4) * 4;  // o_local base
  const int db = (t & 15) * 4;  // d base
  float acc[4][4] = {};
#pragma unroll 4
  for (int e = 0; e < 64; ++e) {
    const fx4 wv = *(const fx4*)&WoT[e * 64 + ob];
    const fx4 kvv = *(const fx4*)&kvT[e * 64 + db];
#pragma unroll
    for (int i = 0; i < 4; ++i)
#pragma unroll
      for (int j = 0; j < 4; ++j)
        acc[i][j] += wv[i] * kvv[j];
  }
#pragma unroll
  for (int i = 0; i < 4; ++i)
#pragma unroll
    for (int j = 0; j < 4; ++j)
      outp[(size_t)(ot * 64 + ob + i) * 1024 + h * 64 + db + j] = f2bf(acc[i][j]);
}

// ---------- fused output GEMMs: out = q @ Weff[b]^T for x and c streams ----------
// grid (8, 136): y -> (b = y/34, local = y%34); local<32 -> x rows, else c rows.
__global__ __launch_bounds__(256) void out_fused(
    const u16* __restrict__ Qx, const u16* __restrict__ Qc,
    const u16* __restrict__ Wex, const u16* __restrict__ Wec,
    float* __restrict__ out) {
  __shared__ __align__(16) u16 As[128 * 64];
  __shared__ __align__(16) u16 Bs[128 * 64];
  const int yt = blockIdx.y;
  const int b = yt / 34;
  const int local = yt - b * 34;
  const bool isC = local >= 32;
  const u16* A;
  const u16* Bw;
  float* C;
  long rowBase;
  if (!isC) {
    A = Qx + (size_t)b * 4194304;
    Bw = Wex + (size_t)b * 1048576;
    C = out + (size_t)b * 4194304;
    rowBase = (long)local * 128;
  } else {
    A = Qc + (size_t)b * 262144;
    Bw = Wec + (size_t)b * 1048576;
    C = out + 16777216 + (size_t)b * 262144;
    rowBase = (long)(local - 32) * 128;
  }
  const long colBase = (long)blockIdx.x * 128;

  fx4 acc[4][4] = {};
  gemm_core_k1024(A, Bw, rowBase, colBase, As, Bs, acc);

  const int t = threadIdx.x;
  const int lane = t & 63;
  const int lr = lane & 15;
  const int quad = lane >> 4;
  const int w = t >> 6;
  const int m0 = (w & 1) * 64;
  const int n0 = (w >> 1) * 64;
#pragma unroll
  for (int mi = 0; mi < 4; ++mi)
#pragma unroll
    for (int ni = 0; ni < 4; ++ni) {
      const long col = colBase + n0 + ni * 16 + lr;
#pragma unroll
      for (int r = 0; r < 4; ++r) {
        const long row = rowBase + m0 + mi * 16 + quad * 4 + r;
        C[row * 1024 + col] = acc[mi][ni][r];
      }
    }
}

// ---------- launch ----------
extern "C" void kernel_launch(void* const* d_in, const int* in_sizes, int n_in,
                              void* d_out, int out_size, void* d_ws, size_t ws_size,
                              hipStream_t stream) {
  (void)in_sizes; (void)n_in; (void)out_size; (void)ws_size;
  const float* x = (const float*)d_in[0];
  const float* c = (const float*)d_in[1];
  const float* nc = (const float*)d_in[10];
  float* out = (float*)d_out;
  char* ws = (char*)d_ws;

  // workspace layout (bytes). total = 177,209,344
  u16* Xb = (u16*)(ws + 0);                 // 33,554,432
  u16* Cb = (u16*)(ws + 33554432);          //  2,097,152
  u16* Wb = (u16*)(ws + 35651584);          // 16,777,216 (8 weights bf16)
  u16* Qx = (u16*)(ws + 52428800);          // 33,554,432
  u16* Qc = (u16*)(ws + 85983232);          //  2,097,152
  u16* Kt = (u16*)(ws + 88080384);          // 35,651,584  [b,h][64 d][4352 n]
  u16* Vt = (u16*)(ws + 123731968);         // 35,651,584
  float* kvb = (float*)(ws + 159383552);    //  1,048,576  kv^T: [bh][e*64+d]
  u16* Weffx = (u16*)(ws + 160432128);      //  8,388,608
  u16* Weffc = (u16*)(ws + 168820736);      //  8,388,608

  cvt_all<<<25600, 256, 0, stream>>>(
      x, c, (const float*)d_in[2], (const float*)d_in[3], (const float*)d_in[4],
      (const float*)d_in[5], (const float*)d_in[6], (const float*)d_in[7],
      (const float*)d_in[8], (const float*)d_in[9], Xb, Cb, Wb);

  // all 6 QKV projections in one dispatch (Q row-major; K,V transposed)
  proj_fused<<<dim3(24, 136), 256, 0, stream>>>(Xb, Cb, Wb, Qx, Qc, Kt, Vt, nc);
  // kv = K^T V per (b,h), MFMA, single dispatch
  kv_mfma<<<64, 256, 0, stream>>>(Kt, Vt, kvb);
  // fold kv into output projections: Weff[b] = blockdiag(kv) applied to Wo
  weff_build<<<dim3(16, 64, 2), 256, 0, stream>>>(Wb + 6 * 1048576, Wb + 7 * 1048576,
                                                  kvb, Weffx, Weffc);
  // both output GEMMs in one dispatch, straight into d_out (fp32)
  out_fused<<<dim3(8, 136), 256, 0, stream>>>(Qx, Qc, Weffx, Weffc, out);
}